// Round 1
// baseline (1853.506 us; speedup 1.0000x reference)
//
#include <hip/hip_runtime.h>
#include <cstdint>
#include <cstddef>

typedef unsigned short u16;
typedef unsigned int u32;

#define E_CNT 640000
#define N_CNT 20000
#define BN_EPS 1e-5f

typedef __attribute__((ext_vector_type(8))) short short8;
typedef __attribute__((ext_vector_type(4))) float floatx4;

__device__ __forceinline__ float bf2f(u16 u){ return __uint_as_float(((u32)u)<<16); }
__device__ __forceinline__ u16 f2bf(float f){
    u32 x = __float_as_uint(f);
    x += 0x7FFFu + ((x>>16)&1u);          // RNE
    return (u16)(x>>16);
}
__device__ __forceinline__ float elu1(float x){ return x>0.f ? x : __expf(x)-1.f; }
// XOR swizzle: element (r,c) of a 128x128 bf16 tile. Keeps 8-element k-groups
// contiguous+16B aligned, 2-way-max bank aliasing on b128 frag reads (free per m136).
__device__ __forceinline__ int swz(int r, int c){ return (r<<7) + (c ^ ((r&15)<<3)); }

__device__ __forceinline__ void bn_affine(const float* st, const float* g, const float* bt,
                                          int c, float invM, float& a, float& cc){
    float mu  = st[c]*invM;
    float var = fmaxf(st[128+c]*invM - mu*mu, 0.f);
    a  = g[c]*rsqrtf(var + BN_EPS);
    cc = bt[c] - mu*a;
}

// ---- MFMA helpers (16x16x32 bf16, verified layouts) -------------------------
// A: m=lane&15, k=(lane>>4)*8+j   B(from W^T): n=lane&15, k=(lane>>4)*8+j
// C/D: col=lane&15, row=(lane>>4)*4+reg
__device__ __forceinline__ void acc_init(const float* __restrict__ b, int l15, floatx4 acc[2][8]){
    #pragma unroll
    for (int nt=0; nt<8; nt++){
        float bv = b[nt*16+l15];
        floatx4 t = {bv,bv,bv,bv};
        acc[0][nt]=t; acc[1][nt]=t;
    }
}
__device__ __forceinline__ void gemm128(const u16* __restrict__ Wt, const u16* XT,
                                        int wr, int l15, int l4, floatx4 acc[2][8]){
    #pragma unroll
    for (int kk=0; kk<4; kk++){
        int k0 = kk*32 + l4*8;
        short8 a0 = *(const short8*)&XT[swz(wr   +l15, k0)];
        short8 a1 = *(const short8*)&XT[swz(wr+16+l15, k0)];
        #pragma unroll
        for (int nt=0; nt<8; nt++){
            short8 b = *(const short8*)(Wt + ((nt*16+l15)<<7) + k0);
            acc[0][nt] = __builtin_amdgcn_mfma_f32_16x16x32_bf16(a0,b,acc[0][nt],0,0,0);
            acc[1][nt] = __builtin_amdgcn_mfma_f32_16x16x32_bf16(a1,b,acc[1][nt],0,0,0);
        }
    }
}

// ---- fused 2-layer MLP: h = ELU(ELU(X@W1+b1)@W2+b2), store bf16 pre-BN + stats
// MODE 0: X fp32.  MODE 1: X bf16 with on-the-fly BN affine from statsIn.
template<int MODE>
__launch_bounds__(256, 2)
__global__ void fused_mlp2(const void* __restrict__ Xin,
    const u16* __restrict__ W1t, const float* __restrict__ b1,
    const u16* __restrict__ W2t, const float* __restrict__ b2,
    u16* __restrict__ Hout, float* __restrict__ statsOut,
    const float* __restrict__ statsIn, const float* __restrict__ gIn,
    const float* __restrict__ btIn, int M, float invPrevM)
{
    __shared__ __align__(16) u16 XT[128*128];
    __shared__ float sca[128], scc[128];
    __shared__ float lsum[128], lsq[128];

    const int tid  = threadIdx.x;
    const int row0 = blockIdx.x << 7;

    if (tid < 128){
        lsum[tid]=0.f; lsq[tid]=0.f;
        if (MODE==1){
            float a,c; bn_affine(statsIn,gIn,btIn,tid,invPrevM,a,c);
            sca[tid]=a; scc[tid]=c;
        }
    }
    __syncthreads();

    if (MODE==0){
        const float* Xf = (const float*)Xin;
        #pragma unroll
        for (int p=0;p<16;p++){
            int idx = p*256+tid;
            int r = idx>>5, c4 = (idx&31)<<2;
            int gr = row0+r;
            float4 v = make_float4(0.f,0.f,0.f,0.f);
            if (gr < M) v = *(const float4*)(Xf + (size_t)gr*128 + c4);
            ushort4 o; o.x=f2bf(v.x); o.y=f2bf(v.y); o.z=f2bf(v.z); o.w=f2bf(v.w);
            *(ushort4*)&XT[swz(r,c4)] = o;
        }
    } else {
        const u16* Xb = (const u16*)Xin;
        #pragma unroll
        for (int p=0;p<8;p++){
            int idx = p*256+tid;
            int r = idx>>4, c8 = (idx&15)<<3;
            int gr = row0+r;
            uint4 v = make_uint4(0u,0u,0u,0u);
            if (gr < M) v = *(const uint4*)(Xb + (size_t)gr*128 + c8);
            u16* u = (u16*)&v;
            u16 o[8];
            #pragma unroll
            for (int j=0;j<8;j++) o[j] = f2bf(sca[c8+j]*bf2f(u[j]) + scc[c8+j]);
            *(uint4*)&XT[swz(r,c8)] = *(uint4*)o;
        }
    }
    __syncthreads();

    const int lane = tid & 63;
    const int l15  = lane & 15, l4 = lane >> 4;
    const int wr   = (tid >> 6) << 5;      // wave's 32-row slice

    floatx4 acc[2][8];
    acc_init(b1, l15, acc);
    gemm128(W1t, XT, wr, l15, l4, acc);
    __syncthreads();                        // all XT/W reads of GEMM1 done

    #pragma unroll
    for (int mt=0; mt<2; mt++)
        #pragma unroll
        for (int nt=0; nt<8; nt++)
            #pragma unroll
            for (int i=0; i<4; i++){
                float v = elu1(acc[mt][nt][i]);
                XT[swz(wr+mt*16+(l4<<2)+i, nt*16+l15)] = f2bf(v);
            }
    acc_init(b2, l15, acc);
    __syncthreads();                        // T1 visible
    gemm128(W2t, XT, wr, l15, l4, acc);
    __syncthreads();                        // GEMM2 XT reads done

    #pragma unroll
    for (int nt=0; nt<8; nt++){
        float s=0.f, q=0.f;
        #pragma unroll
        for (int mt=0; mt<2; mt++)
            #pragma unroll
            for (int i=0; i<4; i++){
                int rloc = wr+mt*16+(l4<<2)+i;
                float v = elu1(acc[mt][nt][i]);
                XT[swz(rloc, nt*16+l15)] = f2bf(v);
                if (row0+rloc < M){ s += v; q += v*v; }
            }
        s += __shfl_xor(s,16,64); s += __shfl_xor(s,32,64);
        q += __shfl_xor(q,16,64); q += __shfl_xor(q,32,64);
        if (lane < 16){
            atomicAdd(&lsum[nt*16+lane], s);
            atomicAdd(&lsq [nt*16+lane], q);
        }
    }
    __syncthreads();
    if (tid < 128){
        atomicAdd(&statsOut[tid],     lsum[tid]);
        atomicAdd(&statsOut[128+tid], lsq[tid]);
    }
    #pragma unroll
    for (int p=0;p<8;p++){
        int idx = p*256+tid;
        int r = idx>>4, c8 = (idx&15)<<3;
        int gr = row0+r;
        if (gr < M){
            uint4 v = *(const uint4*)&XT[swz(r,c8)];
            *(uint4*)(Hout + (size_t)gr*128 + c8) = v;
        }
    }
}

// ---- final edge MLP: t = ELU(edata@eW1a + P[src] + Q[dst] + eb1); ELU(t@eW2+eb2)
__launch_bounds__(256, 2)
__global__ void fused_final(const float* __restrict__ edata,
    const u16* __restrict__ W1t, const float* __restrict__ b1,
    const u16* __restrict__ W2t, const float* __restrict__ b2,
    const u16* __restrict__ P, const u16* __restrict__ Q,
    const int* __restrict__ srcIdx, const int* __restrict__ dstIdx,
    u16* __restrict__ Hout, float* __restrict__ statsOut, int M)
{
    __shared__ __align__(16) u16 XT[128*128];
    __shared__ float lsum[128], lsq[128];
    __shared__ int sIdx[128], dIdx[128];

    const int tid  = threadIdx.x;
    const int row0 = blockIdx.x << 7;

    if (tid < 128){
        lsum[tid]=0.f; lsq[tid]=0.f;
        int gr = row0+tid;
        sIdx[tid] = (gr<M)? srcIdx[gr] : 0;
        dIdx[tid] = (gr<M)? dstIdx[gr] : 0;
    }
    __syncthreads();

    #pragma unroll
    for (int p=0;p<16;p++){
        int idx = p*256+tid;
        int r = idx>>5, c4 = (idx&31)<<2;
        int gr = row0+r;
        float4 v = make_float4(0.f,0.f,0.f,0.f);
        if (gr < M) v = *(const float4*)(edata + (size_t)gr*128 + c4);
        ushort4 o; o.x=f2bf(v.x); o.y=f2bf(v.y); o.z=f2bf(v.z); o.w=f2bf(v.w);
        *(ushort4*)&XT[swz(r,c4)] = o;
    }
    __syncthreads();

    const int lane = tid & 63;
    const int l15  = lane & 15, l4 = lane >> 4;
    const int wr   = (tid >> 6) << 5;

    floatx4 acc[2][8];
    acc_init(b1, l15, acc);
    gemm128(W1t, XT, wr, l15, l4, acc);
    __syncthreads();                        // XT (edata tile) now dead

    // gather PQ = P[src]+Q[dst] into XT (bf16, swizzled layout)
    {
        int r = tid>>1, half = tid&1;
        const u16* Pr = P + (size_t)sIdx[r]*128 + half*64;
        const u16* Qr = Q + (size_t)dIdx[r]*128 + half*64;
        #pragma unroll
        for (int j=0;j<8;j++){
            uint4 pv = *(const uint4*)(Pr + j*8);
            uint4 qv = *(const uint4*)(Qr + j*8);
            u16* pu=(u16*)&pv; u16* qu=(u16*)&qv;
            u16 o[8];
            #pragma unroll
            for (int jj=0;jj<8;jj++) o[jj] = f2bf(bf2f(pu[jj])+bf2f(qu[jj]));
            *(uint4*)&XT[swz(r, half*64 + j*8)] = *(uint4*)o;
        }
    }
    __syncthreads();

    // epilogue1: same-lane read-modify-write of each owned (r,c) slot
    #pragma unroll
    for (int mt=0; mt<2; mt++)
        #pragma unroll
        for (int nt=0; nt<8; nt++)
            #pragma unroll
            for (int i=0; i<4; i++){
                int rloc = wr+mt*16+(l4<<2)+i, c = nt*16+l15;
                float v = acc[mt][nt][i] + bf2f(XT[swz(rloc,c)]);
                XT[swz(rloc,c)] = f2bf(elu1(v));
            }
    acc_init(b2, l15, acc);
    __syncthreads();
    gemm128(W2t, XT, wr, l15, l4, acc);
    __syncthreads();

    #pragma unroll
    for (int nt=0; nt<8; nt++){
        float s=0.f, q=0.f;
        #pragma unroll
        for (int mt=0; mt<2; mt++)
            #pragma unroll
            for (int i=0; i<4; i++){
                int rloc = wr+mt*16+(l4<<2)+i;
                float v = elu1(acc[mt][nt][i]);
                XT[swz(rloc, nt*16+l15)] = f2bf(v);
                if (row0+rloc < M){ s += v; q += v*v; }
            }
        s += __shfl_xor(s,16,64); s += __shfl_xor(s,32,64);
        q += __shfl_xor(q,16,64); q += __shfl_xor(q,32,64);
        if (lane < 16){
            atomicAdd(&lsum[nt*16+lane], s);
            atomicAdd(&lsq [nt*16+lane], q);
        }
    }
    __syncthreads();
    if (tid < 128){
        atomicAdd(&statsOut[tid],     lsum[tid]);
        atomicAdd(&statsOut[128+tid], lsq[tid]);
    }
    #pragma unroll
    for (int p=0;p<8;p++){
        int idx = p*256+tid;
        int r = idx>>4, c8 = (idx&15)<<3;
        int gr = row0+r;
        if (gr < M){
            uint4 v = *(const uint4*)&XT[swz(r,c8)];
            *(uint4*)(Hout + (size_t)gr*128 + c8) = v;
        }
    }
}

// ---- small kernels ----------------------------------------------------------
__global__ void prep_weights(const float* __restrict__ W1s, const float* __restrict__ W2s,
                             const float* __restrict__ eW1, const float* __restrict__ eW2,
                             u16* __restrict__ Wt)
{
    int idx = blockIdx.x*256 + threadIdx.x;     // 10 * 16384
    if (idx >= 10*16384) return;
    int m = idx>>14, rem = idx&16383, n = rem>>7, k = rem&127;
    const float* s;
    if (m<4)      s = W1s + m*16384;
    else if (m<8) s = W2s + (m-4)*16384;
    else if (m==8) s = eW1;                      // rows 0..127
    else          s = eW2;
    Wt[m*16384 + n*128 + k] = f2bf(s[k*128+n]);  // transposed: Wt[n][k]=W[k][n]
}

__global__ void deg_count(const int* __restrict__ dst, int* __restrict__ degcnt){
    int e = blockIdx.x*256 + threadIdx.x;
    if (e < E_CNT) atomicAdd(&degcnt[dst[e]], 1);
}

__global__ void scan20k(const int* __restrict__ degcnt, int* __restrict__ indptr){
    __shared__ int buf[1024];
    __shared__ int carry;
    int tid = threadIdx.x;
    if (tid==0){ carry=0; indptr[0]=0; }
    __syncthreads();
    for (int base=0; base<N_CNT; base+=1024){
        int v = (base+tid<N_CNT)? degcnt[base+tid] : 0;
        buf[tid]=v; __syncthreads();
        for (int off=1; off<1024; off<<=1){
            int t = (tid>=off)? buf[tid-off] : 0;
            __syncthreads();
            buf[tid] += t; __syncthreads();
        }
        if (base+tid<N_CNT) indptr[base+tid+1] = carry + buf[tid];
        __syncthreads();
        if (tid==0) carry += buf[1023];
        __syncthreads();
    }
}

__global__ void csr_fill(const int* __restrict__ dst, const int* __restrict__ indptr,
                         int* __restrict__ cursor, int* __restrict__ eids){
    int e = blockIdx.x*256 + threadIdx.x;
    if (e < E_CNT){
        int d = dst[e];
        int pos = indptr[d] + atomicAdd(&cursor[d], 1);
        eids[pos] = e;
    }
}

// mean over incoming edges of h_e = bn0(h1)+bn1(h2); one wave per node
__global__ void gather_mean(const int* __restrict__ indptr, const int* __restrict__ eids,
    const u16* __restrict__ h1, const u16* __restrict__ h2,
    const float* __restrict__ st0, const float* __restrict__ g0, const float* __restrict__ bt0,
    const float* __restrict__ st1, const float* __restrict__ g1, const float* __restrict__ bt1,
    float* __restrict__ agg)
{
    int gid  = blockIdx.x*256 + threadIdx.x;
    int node = gid >> 6, lane = gid & 63;
    if (node >= N_CNT) return;
    int c0 = lane*2, c1 = c0+1;
    const float invE = 1.f/(float)E_CNT;
    float A0,C0,A0b,C0b,A1,C1,A1b,C1b;
    bn_affine(st0,g0,bt0,c0,invE,A0,C0);  bn_affine(st0,g0,bt0,c1,invE,A0b,C0b);
    bn_affine(st1,g1,bt1,c0,invE,A1,C1);  bn_affine(st1,g1,bt1,c1,invE,A1b,C1b);
    int beg = indptr[node], end = indptr[node+1];
    float s0=0.f, s1=0.f;
    for (int i=beg; i<end; i++){
        int e = eids[i];
        u32 u1 = *(const u32*)(h1 + (size_t)e*128 + c0);
        u32 u2 = *(const u32*)(h2 + (size_t)e*128 + c0);
        s0 += A0 *bf2f((u16)u1)      + C0  + A1 *bf2f((u16)u2)      + C1;
        s1 += A0b*bf2f((u16)(u1>>16))+ C0b + A1b*bf2f((u16)(u2>>16))+ C1b;
    }
    float inv = 1.f/fmaxf((float)(end-beg), 1.f);
    agg[(size_t)node*128 + c0] = s0*inv;
    agg[(size_t)node*128 + c1] = s1*inv;
}

__global__ void make_hn(const u16* __restrict__ h3, const u16* __restrict__ h4,
    const float* __restrict__ st2, const float* __restrict__ g2, const float* __restrict__ bt2,
    const float* __restrict__ st3, const float* __restrict__ g3, const float* __restrict__ bt3,
    float* __restrict__ hn)
{
    __shared__ float a2[128],c2[128],a3[128],c3[128];
    int tid = threadIdx.x;
    if (tid<128){
        bn_affine(st2,g2,bt2,tid,1.f/(float)N_CNT,a2[tid],c2[tid]);
        bn_affine(st3,g3,bt3,tid,1.f/(float)N_CNT,a3[tid],c3[tid]);
    }
    __syncthreads();
    int idx = blockIdx.x*256 + tid;     // == N_CNT*128 exactly
    int c = tid & 127;
    hn[idx] = a3[c]*bf2f(h4[idx])+c3[c] + a2[c]*bf2f(h3[idx])+c2[c];
}

__global__ void make_pq(const float* __restrict__ hn, const float* __restrict__ eW1,
                        u16* __restrict__ P, u16* __restrict__ Q)
{
    int idx = blockIdx.x*256 + threadIdx.x;
    int n = idx>>7, c = idx&127;
    const float* hr = hn + (size_t)n*128;
    const float* Wp = eW1 + 128*128;
    const float* Wq = eW1 + 256*128;
    float sp=0.f, sq=0.f;
    #pragma unroll 4
    for (int k=0;k<128;k++){
        float h = hr[k];
        sp += h*Wp[k*128+c];
        sq += h*Wq[k*128+c];
    }
    P[idx]=f2bf(sp); Q[idx]=f2bf(sq);
}

__global__ void finalize_out(const u16* __restrict__ t2, const float* __restrict__ st,
                             const float* __restrict__ g, const float* __restrict__ bt,
                             float* __restrict__ out)
{
    __shared__ float sa[128], sc[128];
    int tid = threadIdx.x;
    if (tid<128){ bn_affine(st,g,bt,tid,1.f/(float)E_CNT,sa[tid],sc[tid]); }
    __syncthreads();
    size_t idx  = (size_t)blockIdx.x*256 + tid;
    size_t base = idx*8;
    int c8 = (int)(base & 127);
    uint4 v = *(const uint4*)(t2+base);
    const u16* u = (const u16*)&v;
    float4 o0, o1;
    o0.x = sa[c8+0]*bf2f(u[0])+sc[c8+0];
    o0.y = sa[c8+1]*bf2f(u[1])+sc[c8+1];
    o0.z = sa[c8+2]*bf2f(u[2])+sc[c8+2];
    o0.w = sa[c8+3]*bf2f(u[3])+sc[c8+3];
    o1.x = sa[c8+4]*bf2f(u[4])+sc[c8+4];
    o1.y = sa[c8+5]*bf2f(u[5])+sc[c8+5];
    o1.z = sa[c8+6]*bf2f(u[6])+sc[c8+6];
    o1.w = sa[c8+7]*bf2f(u[7])+sc[c8+7];
    *(float4*)(out+base)   = o0;
    *(float4*)(out+base+4) = o1;
}

// ---- workspace layout -------------------------------------------------------
static constexpr size_t SZ_H1    = (size_t)E_CNT*128*2;      // 163,840,000
static constexpr size_t SZ_N16   = (size_t)N_CNT*128*2;      // 5,120,000
static constexpr size_t SZ_N32   = (size_t)N_CNT*128*4;      // 10,240,000
static constexpr size_t OFF_H1   = 0;                        // h1 pre-BN (also reused as t2)
static constexpr size_t OFF_H3   = OFF_H1 + SZ_H1;
static constexpr size_t OFF_H4   = OFF_H3 + SZ_N16;
static constexpr size_t OFF_AGG  = OFF_H4 + SZ_N16;
static constexpr size_t OFF_HN   = OFF_AGG + SZ_N32;
static constexpr size_t OFF_P    = OFF_HN + SZ_N32;
static constexpr size_t OFF_Q    = OFF_P + SZ_N16;
static constexpr size_t OFF_WT   = OFF_Q + SZ_N16;
static constexpr size_t SZ_WT    = (size_t)10*16384*2;
static constexpr size_t OFF_STATS= OFF_WT + SZ_WT;           // 5 stages x (sum[128],sumsq[128])
static constexpr size_t SZ_STATS = (size_t)5*256*4;
static constexpr size_t OFF_DEG  = OFF_STATS + SZ_STATS;
static constexpr size_t OFF_CUR  = OFF_DEG + (size_t)N_CNT*4;
static constexpr size_t OFF_IPTR = OFF_CUR + (size_t)N_CNT*4;
static constexpr size_t OFF_EIDS = OFF_IPTR + (size_t)(N_CNT+1)*4;
// total ~208 MB

extern "C" void kernel_launch(void* const* d_in, const int* in_sizes, int n_in,
                              void* d_out, int out_size, void* d_ws, size_t ws_size,
                              hipStream_t stream)
{
    const float* edata = (const float*)d_in[0];
    const int*   src   = (const int*)  d_in[1];
    const int*   dst   = (const int*)  d_in[2];
    const float* W1s   = (const float*)d_in[4];
    const float* b1s   = (const float*)d_in[5];
    const float* W2s   = (const float*)d_in[6];
    const float* b2s   = (const float*)d_in[7];
    const float* gs    = (const float*)d_in[8];
    const float* bts   = (const float*)d_in[9];
    const float* eW1   = (const float*)d_in[10];
    const float* eb1   = (const float*)d_in[11];
    const float* eW2   = (const float*)d_in[12];
    const float* eb2   = (const float*)d_in[13];
    const float* eg    = (const float*)d_in[14];
    const float* ebt   = (const float*)d_in[15];
    float* out = (float*)d_out;
    char*  ws  = (char*)d_ws;

    u16*   h1     = (u16*)  (ws+OFF_H1);      // also t2 (final pre-BN) later
    u16*   h3     = (u16*)  (ws+OFF_H3);
    u16*   h4     = (u16*)  (ws+OFF_H4);
    float* agg    = (float*)(ws+OFF_AGG);
    float* hn     = (float*)(ws+OFF_HN);
    u16*   P      = (u16*)  (ws+OFF_P);
    u16*   Q      = (u16*)  (ws+OFF_Q);
    u16*   Wt     = (u16*)  (ws+OFF_WT);
    float* stats  = (float*)(ws+OFF_STATS);
    int*   degcnt = (int*)  (ws+OFF_DEG);
    int*   cursor = (int*)  (ws+OFF_CUR);
    int*   indptr = (int*)  (ws+OFF_IPTR);
    int*   eids   = (int*)  (ws+OFF_EIDS);
    u16*   h2     = (u16*)  d_out;            // park h2 (bf16) in d_out; overwritten by finalize

    // zero stats + degcnt + cursor (contiguous)
    hipMemsetAsync(ws+OFF_STATS, 0, SZ_STATS + (size_t)N_CNT*8, stream);

    prep_weights<<<640,256,0,stream>>>(W1s,W2s,eW1,eW2,Wt);
    deg_count   <<<2500,256,0,stream>>>(dst, degcnt);
    scan20k     <<<1,1024,0,stream>>>(degcnt, indptr);
    csr_fill    <<<2500,256,0,stream>>>(dst, indptr, cursor, eids);

    // edge MLP 0: edata -> h1 (pre-BN bf16) + stats0
    fused_mlp2<0><<<5000,256,0,stream>>>(edata, Wt+0*16384, b1s+0,   Wt+4*16384, b2s+0,
                                         h1, stats+0, nullptr,nullptr,nullptr, E_CNT, 0.f);
    // edge MLP 1 (residual branch): bn0(h1) -> h2 (pre-BN bf16) + stats1
    fused_mlp2<1><<<5000,256,0,stream>>>(h1, Wt+1*16384, b1s+128, Wt+5*16384, b2s+128,
                                         h2, stats+256, stats+0, gs+0, bts+0, E_CNT, 1.f/(float)E_CNT);
    // mean aggregation of h_e = bn0(h1)+bn1(h2) over dst
    gather_mean<<<5000,256,0,stream>>>(indptr, eids, h1, h2,
                                       stats+0,   gs+0,   bts+0,
                                       stats+256, gs+128, bts+128, agg);
    // node MLP 2: agg -> h3 + stats2
    fused_mlp2<0><<<157,256,0,stream>>>(agg, Wt+2*16384, b1s+256, Wt+6*16384, b2s+256,
                                        h3, stats+512, nullptr,nullptr,nullptr, N_CNT, 0.f);
    // node MLP 3: bn2(h3) -> h4 + stats3
    fused_mlp2<1><<<157,256,0,stream>>>(h3, Wt+3*16384, b1s+384, Wt+7*16384, b2s+384,
                                        h4, stats+768, stats+512, gs+256, bts+256, N_CNT, 1.f/(float)N_CNT);
    // h_n = bn3(h4) + bn2(h3)
    make_hn<<<10000,256,0,stream>>>(h3,h4, stats+512, gs+256, bts+256,
                                    stats+768, gs+384, bts+384, hn);
    // P = h_n @ eW1[128:256], Q = h_n @ eW1[256:384]
    make_pq<<<10000,256,0,stream>>>(hn, eW1, P, Q);
    // final edge MLP -> t2 (pre-BN bf16, reuses h1 buffer) + stats4
    fused_final<<<5000,256,0,stream>>>(edata, Wt+8*16384, eb1, Wt+9*16384, eb2,
                                       P, Q, src, dst, h1, stats+1024, E_CNT);
    // out = bn4(t2)
    finalize_out<<<40000,256,0,stream>>>(h1, stats+1024, eg, ebt, out);
}